// Round 1
// baseline (346.439 us; speedup 1.0000x reference)
//
#include <hip/hip_runtime.h>

#define ORDER 24
#define W 25              // row width = ORDER + 1
#define ROWS_PER_BLOCK 256
#define THREADS 256

// Levinson recursion: PARCOR (reflection) -> LPC coefficients, one thread/row.
// Rows are 100 B (not 16 B aligned), so stage 256 rows per block through LDS:
// global<->LDS is pure float4-coalesced (block chunk = 25600 B = 1600 float4,
// 16 B aligned); per-thread LDS row access at stride 25 floats is a bank
// permutation (25 odd) -> 2 lanes/bank per wave64 -> conflict-free.
__global__ __launch_bounds__(THREADS)
void parcor2lpc_kernel(const float* __restrict__ in,
                       float* __restrict__ out, int rows)
{
    __shared__ float lds[ROWS_PER_BLOCK * W];   // 25.6 KB -> 6 blocks/CU

    const int t = threadIdx.x;
    const long long row0 = (long long)blockIdx.x * ROWS_PER_BLOCK;
    const long long base = row0 * W;            // float offset of block chunk
    const long long rem  = (long long)rows - row0;
    const int nrows = rem >= ROWS_PER_BLOCK ? ROWS_PER_BLOCK : (int)rem;

    if (nrows == ROWS_PER_BLOCK) {
        // fast path: 6400 floats = 1600 float4, base byte offset % 16 == 0
        const float4* __restrict__ gin = (const float4*)(in + base);
        float4* sv = (float4*)lds;
        #pragma unroll
        for (int i = t; i < (ROWS_PER_BLOCK * W) / 4; i += THREADS)
            sv[i] = gin[i];
    } else {
        for (int i = t; i < nrows * W; i += THREADS)
            lds[i] = in[base + i];
    }
    __syncthreads();

    if (t < nrows) {
        float a[W];
        #pragma unroll
        for (int j = 0; j < W; ++j) a[j] = lds[t * W + j];

        // a[m] is unmodified before step m, so k[m] == a[m] here.
        #pragma unroll
        for (int m = 2; m <= ORDER; ++m) {
            const float km = a[m];
            #pragma unroll
            for (int j = 1; j <= (m - 1) / 2; ++j) {
                const float lo = a[j], hi = a[m - j];
                a[j]     = fmaf(km, hi, lo);
                a[m - j] = fmaf(km, lo, hi);
            }
            if ((m & 1) == 0) {              // self-paired middle element
                const float v = a[m / 2];
                a[m / 2] = fmaf(km, v, v);
            }
        }

        // no barrier needed between read & write-back: each thread touches
        // only its own row
        #pragma unroll
        for (int j = 0; j < W; ++j) lds[t * W + j] = a[j];
    }
    __syncthreads();

    if (nrows == ROWS_PER_BLOCK) {
        float4* __restrict__ gout = (float4*)(out + base);
        const float4* sv = (const float4*)lds;
        #pragma unroll
        for (int i = t; i < (ROWS_PER_BLOCK * W) / 4; i += THREADS)
            gout[i] = sv[i];
    } else {
        for (int i = t; i < nrows * W; i += THREADS)
            out[base + i] = lds[i];
    }
}

extern "C" void kernel_launch(void* const* d_in, const int* in_sizes, int n_in,
                              void* d_out, int out_size, void* d_ws, size_t ws_size,
                              hipStream_t stream) {
    const float* k = (const float*)d_in[0];
    float* out = (float*)d_out;
    const int rows = in_sizes[0] / W;                 // 2,097,152
    const int grid = (rows + ROWS_PER_BLOCK - 1) / ROWS_PER_BLOCK;  // 8192
    parcor2lpc_kernel<<<grid, THREADS, 0, stream>>>(k, out, rows);
}